// Round 1
// baseline (236.160 us; speedup 1.0000x reference)
//
#include <hip/hip_runtime.h>
#include <math.h>

#define BB 16
#define NN 256
#define DD 64
#define KTOP 128

__device__ __forceinline__ float fast_tanh(float xx) {
    float ax = fabsf(xx);
    float e  = __expf(2.0f * ax);
    float t  = 1.0f - 2.0f / (e + 1.0f);
    return copysignf(t, xx);
}

// Kernel 1: logits[b,i,j] = (1/TEMP) * att_w . tanh((x_i*x_j) @ W_att + b_att)
// Block: (jt, it, b) covers j-tile of 64, i-tile of 4, one batch.
// 256 threads: i_loc = tid>>6 (4), r = tid&63 -> tj=r&7 (8 j-groups), te=r>>3 (8 e-groups).
// Each thread: 8x8 register tile over (j,e) of the 256x64x64 per-(b,i) matmul.
__global__ __launch_bounds__(256) void k_logits(
    const float* __restrict__ x, const float* __restrict__ W_att,
    const float* __restrict__ b_att, const float* __restrict__ att_w,
    float* __restrict__ logits)
{
    const int jt  = blockIdx.x;   // 0..3
    const int it  = blockIdx.y;   // 0..63
    const int b   = blockIdx.z;   // 0..15
    const int tid = threadIdx.x;

    __shared__ float sW[64 * 64];      // W_att[d][e]
    __shared__ float sXT[64 * 68];     // x^T tile: [d][j_loc], stride 68 (16B aligned, 2-way banks on read)
    __shared__ float sXi[4 * 64];      // 4 i-rows
    __shared__ float sAw[64];
    __shared__ float sBat[64];
    __shared__ float sRed[4 * 64 * 8]; // partial logits reduction [i_loc][j_loc][te]

    for (int k = tid; k < 4096; k += 256) sW[k] = W_att[k];
    if (tid < 64) { sAw[tid] = att_w[tid]; sBat[tid] = b_att[tid]; }
    {
        int il = tid >> 6, d = tid & 63;
        sXi[tid] = x[((b * NN) + it * 4 + il) * DD + d];
    }
    const int jb = jt * 64;
    #pragma unroll
    for (int r = 0; r < 16; ++r) {
        int lin = r * 256 + tid;
        int j = lin >> 6, d = lin & 63;
        sXT[d * 68 + j] = x[((b * NN) + jb + j) * DD + d];
    }
    __syncthreads();

    const int il = tid >> 6;
    const int rr = tid & 63;
    const int tj = rr & 7, te = rr >> 3;
    const int j8 = tj * 8, e8 = te * 8;

    float acc[8][8];
    #pragma unroll
    for (int q = 0; q < 8; ++q)
        #pragma unroll
        for (int p = 0; p < 8; ++p) acc[q][p] = 0.0f;

    const float* xiB = &sXi[il * 64];
    #pragma unroll 4
    for (int d = 0; d < 64; ++d) {
        const float4 a0 = *(const float4*)&sXT[d * 68 + j8];
        const float4 a1 = *(const float4*)&sXT[d * 68 + j8 + 4];
        const float4 w0 = *(const float4*)&sW[d * 64 + e8];
        const float4 w1 = *(const float4*)&sW[d * 64 + e8 + 4];
        const float xd = xiB[d];
        float am[8] = { xd * a0.x, xd * a0.y, xd * a0.z, xd * a0.w,
                        xd * a1.x, xd * a1.y, xd * a1.z, xd * a1.w };
        float wv[8] = { w0.x, w0.y, w0.z, w0.w, w1.x, w1.y, w1.z, w1.w };
        #pragma unroll
        for (int q = 0; q < 8; ++q)
            #pragma unroll
            for (int p = 0; p < 8; ++p)
                acc[q][p] = fmaf(am[q], wv[p], acc[q][p]);
    }

    // per-thread partial logits over this thread's 8 e's, for its 8 j's
    #pragma unroll
    for (int q = 0; q < 8; ++q) {
        float s = 0.0f;
        #pragma unroll
        for (int p = 0; p < 8; ++p)
            s += sAw[e8 + p] * fast_tanh(acc[q][p] + sBat[e8 + p]);
        sRed[(il * 64 + j8 + q) * 8 + te] = s;
    }
    __syncthreads();
    {
        int i2 = tid >> 6, jl = tid & 63;
        const float* rb = &sRed[(i2 * 64 + jl) * 8];
        float s = rb[0] + rb[1] + rb[2] + rb[3] + rb[4] + rb[5] + rb[6] + rb[7];
        logits[((b * NN) + it * 4 + i2) * NN + jb + jl] = s * 0.5f;  // 1/TEMP
    }
}

// Kernel 2: softmax over j, agg = A@x, h = agg@W_pwa + x@W_pna + biases, BN, selu,
// score = sigmoid(h.pool_w + pool_b). One wave per (b,i); 4 waves/block.
__global__ __launch_bounds__(256) void k_soft(
    const float* __restrict__ x, const float* __restrict__ logits,
    const float* __restrict__ Wpwa, const float* __restrict__ bpwa,
    const float* __restrict__ Wpna, const float* __restrict__ bpna,
    const float* __restrict__ bnsc, const float* __restrict__ bnbi,
    const float* __restrict__ poolw, const float* __restrict__ poolb,
    float* __restrict__ hbuf, float* __restrict__ scores)
{
    const int bx   = blockIdx.x;        // 0..1023
    const int b    = bx >> 6;
    const int ig   = bx & 63;
    const int w    = threadIdx.x >> 6;
    const int lane = threadIdx.x & 63;
    const int i    = ig * 4 + w;

    __shared__ float sA[4][256];
    __shared__ float sAgg[4][64];
    __shared__ float sXi[4][64];

    const float* row = &logits[((b * NN) + i) * NN];
    float lg0 = row[lane], lg1 = row[lane + 64], lg2 = row[lane + 128], lg3 = row[lane + 192];
    float m = fmaxf(fmaxf(lg0, lg1), fmaxf(lg2, lg3));
    #pragma unroll
    for (int off = 32; off; off >>= 1) m = fmaxf(m, __shfl_xor(m, off));
    float e0 = __expf(lg0 - m), e1 = __expf(lg1 - m), e2 = __expf(lg2 - m), e3 = __expf(lg3 - m);
    float ssum = e0 + e1 + e2 + e3;
    #pragma unroll
    for (int off = 32; off; off >>= 1) ssum += __shfl_xor(ssum, off);
    float inv = 1.0f / ssum;
    sA[w][lane] = e0 * inv; sA[w][lane + 64] = e1 * inv;
    sA[w][lane + 128] = e2 * inv; sA[w][lane + 192] = e3 * inv;
    sXi[w][lane] = x[((b * NN) + i) * DD + lane];
    __syncthreads();

    // agg[d]: lane = d
    float agg = 0.0f;
    const float4* A4 = (const float4*)&sA[w][0];
    const float* xb = &x[(b * NN) * DD];
    #pragma unroll 4
    for (int jq = 0; jq < 64; ++jq) {
        float4 a = A4[jq];
        int j = jq * 4;
        agg = fmaf(a.x, xb[(j + 0) * DD + lane], agg);
        agg = fmaf(a.y, xb[(j + 1) * DD + lane], agg);
        agg = fmaf(a.z, xb[(j + 2) * DD + lane], agg);
        agg = fmaf(a.w, xb[(j + 3) * DD + lane], agg);
    }
    sAgg[w][lane] = agg;
    __syncthreads();

    // h[e]: lane = e.  fp64 accumulation to keep score-ordering fidelity.
    double hacc = (double)bpwa[lane] + (double)bpna[lane];
    #pragma unroll 4
    for (int d = 0; d < 64; ++d) {
        hacc += (double)sAgg[w][d] * (double)Wpwa[d * DD + lane]
              + (double)sXi[w][d]  * (double)Wpna[d * DD + lane];
    }
    const double bnmul = 0.99999500003749968750e0; // 1/sqrt(1+1e-5)
    double hb = hacc * ((double)bnsc[lane] * bnmul) + (double)bnbi[lane];
    float hf = (float)hb;
    const float LAM = 1.0507009873554805f, ALP = 1.6732632423543772f;
    float hs = hf > 0.0f ? LAM * hf : LAM * ALP * (__expf(hf) - 1.0f);
    hbuf[((b * NN) + i) * DD + lane] = hs;

    double z = (double)hs * (double)poolw[lane];
    #pragma unroll
    for (int off = 32; off; off >>= 1) z += __shfl_xor(z, off);
    if (lane == 0) {
        double zz = z + (double)poolb[0];
        scores[b * NN + i] = (float)(1.0 / (1.0 + exp(-zz)));
    }
}

// Kernel 3: per-batch bitonic sort of 256 scores (desc, tie: lower idx first) + gather top-128.
__global__ __launch_bounds__(256) void k_topk(
    const float* __restrict__ scores, const float* __restrict__ hbuf,
    float* __restrict__ out)
{
    const int b = blockIdx.x;
    const int t = threadIdx.x;
    __shared__ float ss[256];
    __shared__ int   si[256];
    ss[t] = scores[b * NN + t];
    si[t] = t;
    __syncthreads();
    for (int k = 2; k <= 256; k <<= 1) {
        for (int j = k >> 1; j > 0; j >>= 1) {
            int p = t ^ j;
            if (p > t) {
                float a = ss[t], c = ss[p];
                int ia = si[t], ic = si[p];
                bool desc = ((t & k) == 0);
                bool aFirst = (a > c) || (a == c && ia < ic); // total order: score desc, idx asc
                bool dosw = desc ? (!aFirst) : aFirst;
                if (dosw) { ss[t] = c; ss[p] = a; si[t] = ic; si[p] = ia; }
            }
            __syncthreads();
        }
    }
    for (int m = t; m < KTOP * DD; m += 256) {
        int r = m >> 6, e = m & 63;
        out[(b * KTOP + r) * DD + e] = hbuf[((b * NN) + si[r]) * DD + e] * ss[r];
    }
}

extern "C" void kernel_launch(void* const* d_in, const int* in_sizes, int n_in,
                              void* d_out, int out_size, void* d_ws, size_t ws_size,
                              hipStream_t stream) {
    const float* x        = (const float*)d_in[0];
    const float* W_att    = (const float*)d_in[1];
    const float* b_att    = (const float*)d_in[2];
    const float* att_w    = (const float*)d_in[3];
    const float* W_pwa    = (const float*)d_in[4];
    const float* b_pwa    = (const float*)d_in[5];
    const float* W_pna    = (const float*)d_in[6];
    const float* b_pna    = (const float*)d_in[7];
    const float* bn_scale = (const float*)d_in[8];
    const float* bn_bias  = (const float*)d_in[9];
    const float* pool_w   = (const float*)d_in[10];
    const float* pool_b   = (const float*)d_in[11];

    float* logits = (float*)d_ws;                 // 16*256*256
    float* hbuf   = logits + BB * NN * NN;        // 16*256*64
    float* scoresW = hbuf + BB * NN * DD;         // 16*256
    float* out    = (float*)d_out;

    k_logits<<<dim3(4, 64, BB), 256, 0, stream>>>(x, W_att, b_att, att_w, logits);
    k_soft<<<dim3(BB * 64), 256, 0, stream>>>(x, logits, W_pwa, b_pwa, W_pna, b_pna,
                                              bn_scale, bn_bias, pool_w, pool_b,
                                              hbuf, scoresW);
    k_topk<<<dim3(BB), 256, 0, stream>>>(scoresW, hbuf, out);
}

// Round 2
// 152.865 us; speedup vs baseline: 1.5449x; 1.5449x over previous
//
#include <hip/hip_runtime.h>
#include <math.h>

#define BB 16
#define NN 256
#define DD 64
#define KTOP 128

typedef short s16x8 __attribute__((ext_vector_type(8)));
typedef float f32x4 __attribute__((ext_vector_type(4)));

__device__ __forceinline__ unsigned asu(float f){ union{float f;unsigned u;}c; c.f=f; return c.u; }
__device__ __forceinline__ float asf(unsigned u){ union{unsigned u;float f;}c; c.u=u; return c.f; }

// Kernel 1 (MFMA): logits[b,i,j] = (1/TEMP) * att_w . tanh((x_i*x_j) @ W_att + b_att)
// Per block: one b, 4 i's. 4 waves; wave w owns j-strip [64w,64w+64).
// C_i[j,e] = sum_d x_j[d] * (x_i[d]*W[d,e]).  A = x_j (split hi/lo bf16, regs, built once).
// B = x_i .* W columns (built per i from LDS W^T + sXi, split hi/lo).  3 MFMA passes:
// AhBh + AlBh + AhBl -> rel err ~2^-15, keeps top-k score ordering exact.
__global__ __launch_bounds__(256, 2) void k_logits(
    const float* __restrict__ x, const float* __restrict__ W_att,
    const float* __restrict__ b_att, const float* __restrict__ att_w,
    float* __restrict__ logits)
{
    const int ig = blockIdx.x;     // 0..63 : i-group of 4
    const int b  = blockIdx.y;     // 0..15
    const int tid = threadIdx.x;
    const int w = tid >> 6, lane = tid & 63;
    const int quad = lane >> 4, c16 = lane & 15;
    const int jb = w * 64;
    const int ibase = ig * 4;

    __shared__ float sWt[64 * 68];   // W^T: [e][d], stride 68 (16B-aligned rows, 2-way banks on b128)
    __shared__ float sXi[4 * 64];    // the block's 4 x_i rows
    __shared__ float sLog[4][64];    // per-wave logit staging

    // ---- setup (once per block) ----
    #pragma unroll
    for (int r = 0; r < 16; ++r) {
        int lin = r * 256 + tid;
        int d = lin >> 6, e = lin & 63;
        sWt[e * 68 + d] = W_att[lin];
    }
    sXi[tid] = x[(b * NN + ibase + (tid >> 6)) * DD + (tid & 63)];

    float baw[4], aww[4];
    #pragma unroll
    for (int et = 0; et < 4; ++et) {
        baw[et] = b_att[et * 16 + c16];
        aww[et] = att_w[et * 16 + c16];
    }

    // A fragments: A[m=c16][k=quad*8+t] = x[b][jb+jt*16+c16][ks*32+quad*8+t], split hi/lo
    s16x8 Ah[4][2], Al[4][2];
    #pragma unroll
    for (int jt = 0; jt < 4; ++jt) {
        #pragma unroll
        for (int ks = 0; ks < 2; ++ks) {
            const float* xr = &x[(b * NN + jb + jt * 16 + c16) * DD + ks * 32 + quad * 8];
            float4 a0 = *(const float4*)xr;
            float4 a1 = *(const float4*)(xr + 4);
            float av[8] = {a0.x,a0.y,a0.z,a0.w,a1.x,a1.y,a1.z,a1.w};
            s16x8 h, l;
            #pragma unroll
            for (int t = 0; t < 8; ++t) {
                unsigned u = asu(av[t]);
                h[t] = (short)(u >> 16);                 // truncated hi
                float lf = av[t] - asf(u & 0xffff0000u); // exact residual
                l[t] = (short)(asu(lf) >> 16);
            }
            Ah[jt][ks] = h; Al[jt][ks] = l;
        }
    }
    __syncthreads();

    for (int ii = 0; ii < 4; ++ii) {
        // x_i slice for this lane's k indices (broadcast LDS reads, conflict-free)
        float xi[2][8];
        #pragma unroll
        for (int ks = 0; ks < 2; ++ks) {
            const float* xr = &sXi[ii * 64 + ks * 32 + quad * 8];
            float4 c0 = *(const float4*)xr;
            float4 c1 = *(const float4*)(xr + 4);
            xi[ks][0]=c0.x; xi[ks][1]=c0.y; xi[ks][2]=c0.z; xi[ks][3]=c0.w;
            xi[ks][4]=c1.x; xi[ks][5]=c1.y; xi[ks][6]=c1.z; xi[ks][7]=c1.w;
        }

        f32x4 acc[4][4];
        #pragma unroll
        for (int jt = 0; jt < 4; ++jt)
            #pragma unroll
            for (int et = 0; et < 4; ++et)
                acc[jt][et] = (f32x4){0.f, 0.f, 0.f, 0.f};

        #pragma unroll
        for (int ks = 0; ks < 2; ++ks) {
            #pragma unroll
            for (int et = 0; et < 4; ++et) {
                // B fragment: B[k=quad*8+t][n=c16] = x_i[d]*W[d][et*16+c16], d=ks*32+quad*8+t
                const float* wrow = &sWt[(et * 16 + c16) * 68 + ks * 32 + quad * 8];
                float4 w0 = *(const float4*)wrow;
                float4 w1 = *(const float4*)(wrow + 4);
                float wv[8] = {w0.x,w0.y,w0.z,w0.w,w1.x,w1.y,w1.z,w1.w};
                s16x8 bh, bl;
                #pragma unroll
                for (int t = 0; t < 8; ++t) {
                    float v = wv[t] * xi[ks][t];
                    unsigned u = asu(v);
                    bh[t] = (short)(u >> 16);
                    float lf = v - asf(u & 0xffff0000u);
                    bl[t] = (short)(asu(lf) >> 16);
                }
                #pragma unroll
                for (int jt = 0; jt < 4; ++jt) {
                    acc[jt][et] = __builtin_amdgcn_mfma_f32_16x16x32_bf16(Ah[jt][ks], bh, acc[jt][et], 0, 0, 0);
                    acc[jt][et] = __builtin_amdgcn_mfma_f32_16x16x32_bf16(Al[jt][ks], bh, acc[jt][et], 0, 0, 0);
                    acc[jt][et] = __builtin_amdgcn_mfma_f32_16x16x32_bf16(Ah[jt][ks], bl, acc[jt][et], 0, 0, 0);
                }
            }
        }

        // epilogue: tanh + att_w-dot over e.  C/D layout: row=quad*4+r (j), col=c16 (e).
        float p[4][4];
        #pragma unroll
        for (int jt = 0; jt < 4; ++jt)
            #pragma unroll
            for (int r = 0; r < 4; ++r) p[jt][r] = 0.0f;

        #pragma unroll
        for (int et = 0; et < 4; ++et) {
            #pragma unroll
            for (int jt = 0; jt < 4; ++jt) {
                #pragma unroll
                for (int r = 0; r < 4; ++r) {
                    float v = acc[jt][et][r] + baw[et];
                    // tanh(v) = 1 - 2/(e^{2v}+1); saturates correctly for |v| large
                    float m = __expf(v + v);
                    float th = fmaf(-2.0f, __builtin_amdgcn_rcpf(m + 1.0f), 1.0f);
                    p[jt][r] = fmaf(aww[et], th, p[jt][r]);
                }
            }
        }

        // reduce over the 16 e-columns held across lanes (xor 1,2,4,8 stays in quad)
        #pragma unroll
        for (int jt = 0; jt < 4; ++jt) {
            #pragma unroll
            for (int r = 0; r < 4; ++r) {
                float s = p[jt][r];
                s += __shfl_xor(s, 1);
                s += __shfl_xor(s, 2);
                s += __shfl_xor(s, 4);
                s += __shfl_xor(s, 8);
                if (c16 == 0) sLog[w][jt * 16 + quad * 4 + r] = s;
            }
        }
        __asm__ volatile("s_waitcnt lgkmcnt(0)" ::: "memory");
        float lv = sLog[w][lane];
        logits[(b * NN + ibase + ii) * NN + jb + lane] = lv * 0.5f;  // 1/TEMP
    }
}

// Kernel 2: softmax over j, agg = A@x, h = agg@W_pwa + x@W_pna + biases, BN, selu,
// score = sigmoid(h.pool_w + pool_b). One wave per (b,i); 4 waves/block.
__global__ __launch_bounds__(256) void k_soft(
    const float* __restrict__ x, const float* __restrict__ logits,
    const float* __restrict__ Wpwa, const float* __restrict__ bpwa,
    const float* __restrict__ Wpna, const float* __restrict__ bpna,
    const float* __restrict__ bnsc, const float* __restrict__ bnbi,
    const float* __restrict__ poolw, const float* __restrict__ poolb,
    float* __restrict__ hbuf, float* __restrict__ scores)
{
    const int bx   = blockIdx.x;        // 0..1023
    const int b    = bx >> 6;
    const int ig   = bx & 63;
    const int w    = threadIdx.x >> 6;
    const int lane = threadIdx.x & 63;
    const int i    = ig * 4 + w;

    __shared__ float sA[4][256];
    __shared__ float sAgg[4][64];
    __shared__ float sXi[4][64];

    const float* row = &logits[((b * NN) + i) * NN];
    float lg0 = row[lane], lg1 = row[lane + 64], lg2 = row[lane + 128], lg3 = row[lane + 192];
    float m = fmaxf(fmaxf(lg0, lg1), fmaxf(lg2, lg3));
    #pragma unroll
    for (int off = 32; off; off >>= 1) m = fmaxf(m, __shfl_xor(m, off));
    float e0 = __expf(lg0 - m), e1 = __expf(lg1 - m), e2 = __expf(lg2 - m), e3 = __expf(lg3 - m);
    float ssum = e0 + e1 + e2 + e3;
    #pragma unroll
    for (int off = 32; off; off >>= 1) ssum += __shfl_xor(ssum, off);
    float inv = 1.0f / ssum;
    sA[w][lane] = e0 * inv; sA[w][lane + 64] = e1 * inv;
    sA[w][lane + 128] = e2 * inv; sA[w][lane + 192] = e3 * inv;
    sXi[w][lane] = x[((b * NN) + i) * DD + lane];
    __syncthreads();

    // agg[d]: lane = d
    float agg = 0.0f;
    const float4* A4 = (const float4*)&sA[w][0];
    const float* xb = &x[(b * NN) * DD];
    #pragma unroll 4
    for (int jq = 0; jq < 64; ++jq) {
        float4 a = A4[jq];
        int j = jq * 4;
        agg = fmaf(a.x, xb[(j + 0) * DD + lane], agg);
        agg = fmaf(a.y, xb[(j + 1) * DD + lane], agg);
        agg = fmaf(a.z, xb[(j + 2) * DD + lane], agg);
        agg = fmaf(a.w, xb[(j + 3) * DD + lane], agg);
    }
    sAgg[w][lane] = agg;
    __syncthreads();

    // h[e]: lane = e.  fp64 accumulation to keep score-ordering fidelity.
    double hacc = (double)bpwa[lane] + (double)bpna[lane];
    #pragma unroll 4
    for (int d = 0; d < 64; ++d) {
        hacc += (double)sAgg[w][d] * (double)Wpwa[d * DD + lane]
              + (double)sXi[w][d]  * (double)Wpna[d * DD + lane];
    }
    const double bnmul = 0.99999500003749968750e0; // 1/sqrt(1+1e-5)
    double hb = hacc * ((double)bnsc[lane] * bnmul) + (double)bnbi[lane];
    float hf = (float)hb;
    const float LAM = 1.0507009873554805f, ALP = 1.6732632423543772f;
    float hs = hf > 0.0f ? LAM * hf : LAM * ALP * (__expf(hf) - 1.0f);
    hbuf[((b * NN) + i) * DD + lane] = hs;

    double z = (double)hs * (double)poolw[lane];
    #pragma unroll
    for (int off = 32; off; off >>= 1) z += __shfl_xor(z, off);
    if (lane == 0) {
        double zz = z + (double)poolb[0];
        scores[b * NN + i] = (float)(1.0 / (1.0 + exp(-zz)));
    }
}

// Kernel 3: per-batch bitonic sort of 256 scores (desc, tie: lower idx first) + gather top-128.
__global__ __launch_bounds__(256) void k_topk(
    const float* __restrict__ scores, const float* __restrict__ hbuf,
    float* __restrict__ out)
{
    const int b = blockIdx.x;
    const int t = threadIdx.x;
    __shared__ float ss[256];
    __shared__ int   si[256];
    ss[t] = scores[b * NN + t];
    si[t] = t;
    __syncthreads();
    for (int k = 2; k <= 256; k <<= 1) {
        for (int j = k >> 1; j > 0; j >>= 1) {
            int p = t ^ j;
            if (p > t) {
                float a = ss[t], c = ss[p];
                int ia = si[t], ic = si[p];
                bool desc = ((t & k) == 0);
                bool aFirst = (a > c) || (a == c && ia < ic); // total order: score desc, idx asc
                bool dosw = desc ? (!aFirst) : aFirst;
                if (dosw) { ss[t] = c; ss[p] = a; si[t] = ic; si[p] = ia; }
            }
            __syncthreads();
        }
    }
    for (int m = t; m < KTOP * DD; m += 256) {
        int r = m >> 6, e = m & 63;
        out[(b * KTOP + r) * DD + e] = hbuf[((b * NN) + si[r]) * DD + e] * ss[r];
    }
}

extern "C" void kernel_launch(void* const* d_in, const int* in_sizes, int n_in,
                              void* d_out, int out_size, void* d_ws, size_t ws_size,
                              hipStream_t stream) {
    const float* x        = (const float*)d_in[0];
    const float* W_att    = (const float*)d_in[1];
    const float* b_att    = (const float*)d_in[2];
    const float* att_w    = (const float*)d_in[3];
    const float* W_pwa    = (const float*)d_in[4];
    const float* b_pwa    = (const float*)d_in[5];
    const float* W_pna    = (const float*)d_in[6];
    const float* b_pna    = (const float*)d_in[7];
    const float* bn_scale = (const float*)d_in[8];
    const float* bn_bias  = (const float*)d_in[9];
    const float* pool_w   = (const float*)d_in[10];
    const float* pool_b   = (const float*)d_in[11];

    float* logits = (float*)d_ws;                 // 16*256*256
    float* hbuf   = logits + BB * NN * NN;        // 16*256*64
    float* scoresW = hbuf + BB * NN * DD;         // 16*256
    float* out    = (float*)d_out;

    k_logits<<<dim3(64, BB), 256, 0, stream>>>(x, W_att, b_att, att_w, logits);
    k_soft<<<dim3(BB * 64), 256, 0, stream>>>(x, logits, W_pwa, b_pwa, W_pna, b_pna,
                                              bn_scale, bn_bias, pool_w, pool_b,
                                              hbuf, scoresW);
    k_topk<<<dim3(BB), 256, 0, stream>>>(scoresW, hbuf, out);
}